// Round 1
// baseline (655.113 us; speedup 1.0000x reference)
//
#include <hip/hip_runtime.h>

typedef short s16x8 __attribute__((ext_vector_type(8)));
typedef float f32x4 __attribute__((ext_vector_type(4)));

#define MFMA_BF16(a, b, c) __builtin_amdgcn_mfma_f32_16x16x32_bf16((a), (b), (c), 0, 0, 0)

// fp32 -> bf16 bits, round-nearest-even (inputs are finite; no NaN path needed)
__device__ __forceinline__ unsigned short f2b(float f) {
  unsigned int u = __builtin_bit_cast(unsigned int, f);
  unsigned int r = u + 0x7FFFu + ((u >> 16) & 1u);
  return (unsigned short)(r >> 16);
}
__device__ __forceinline__ unsigned int pk2(float a, float b) {
  return (unsigned int)f2b(a) | ((unsigned int)f2b(b) << 16);
}
__device__ __forceinline__ float fast_exp2(float x) {
#if __has_builtin(__builtin_amdgcn_exp2f)
  return __builtin_amdgcn_exp2f(x);
#else
  return exp2f(x);
#endif
}

// ---------------------------------------------------------------------------
// Weight transpose + cast: T[n][k] = bf16(W[k][n]), 1024x1024, z selects matrix
// ---------------------------------------------------------------------------
__global__ void wtrans(const float* __restrict__ W0, const float* __restrict__ W1,
                       const float* __restrict__ W2, const float* __restrict__ W3,
                       unsigned short* __restrict__ T0, unsigned short* __restrict__ T1,
                       unsigned short* __restrict__ T2, unsigned short* __restrict__ T3) {
  const float* W;
  unsigned short* T;
  switch (blockIdx.z) {
    case 0: W = W0; T = T0; break;
    case 1: W = W1; T = T1; break;
    case 2: W = W2; T = T2; break;
    default: W = W3; T = T3; break;
  }
  __shared__ float tile[32][33];
  const int n0 = blockIdx.x << 5;
  const int k0 = blockIdx.y << 5;
  const int tx = threadIdx.x;
  const int ty = threadIdx.y;
#pragma unroll
  for (int j = 0; j < 4; ++j)
    tile[ty + 8 * j][tx] = W[(size_t)(k0 + ty + 8 * j) * 1024 + n0 + tx];
  __syncthreads();
#pragma unroll
  for (int j = 0; j < 4; ++j)
    T[(size_t)(n0 + ty + 8 * j) * 1024 + k0 + tx] = f2b(tile[tx][ty + 8 * j]);
}

// ---------------------------------------------------------------------------
// GEMM: C[8192,1024] = A[8192,1024] @ Bt[1024,1024]^T + bias
// MODE 0: A fp32, store bf16 to [B,H,S,D]           (q, k)
// MODE 1: A fp32, store bf16 transposed [B,H,D,S]   (v)
// MODE 2: A bf16(ushort), store fp32 row-major      (output projection)
// block = 256 (4 waves 2x2), tile 128x128, BK=32
// ---------------------------------------------------------------------------
template <int MODE>
__global__ __launch_bounds__(256, 2) void gemm_bt(const void* __restrict__ Ain,
                                                  const unsigned short* __restrict__ Bt,
                                                  const float* __restrict__ bias,
                                                  void* __restrict__ Cout) {
  __shared__ unsigned short As[128][40];  // stride 80 B (16B-aligned rows)
  __shared__ unsigned short Bs[128][40];
  const int n0 = blockIdx.x * 128;
  const int m0 = blockIdx.y * 128;
  const int tid = threadIdx.x;
  const int srow = tid >> 1;
  const int kc = (tid & 1) << 4;
  const int w = tid >> 6;
  const int lane = tid & 63;
  const int lr = lane & 15;
  const int lg = lane >> 4;
  const int wm = (w >> 1) << 6;
  const int wn = (w & 1) << 6;

  f32x4 acc[4][4];
#pragma unroll
  for (int i = 0; i < 4; ++i)
#pragma unroll
    for (int j = 0; j < 4; ++j) {
      f32x4 z = {0.f, 0.f, 0.f, 0.f};
      acc[i][j] = z;
    }

  const unsigned short* Bp0 = Bt + (size_t)(n0 + srow) * 1024 + kc;

  for (int k0 = 0; k0 < 1024; k0 += 32) {
    if constexpr (MODE != 2) {
      const float* A = (const float*)Ain + (size_t)(m0 + srow) * 1024 + k0 + kc;
      float4 f0 = ((const float4*)A)[0];
      float4 f1 = ((const float4*)A)[1];
      float4 f2 = ((const float4*)A)[2];
      float4 f3 = ((const float4*)A)[3];
      uint4 u0, u1;
      u0.x = pk2(f0.x, f0.y); u0.y = pk2(f0.z, f0.w);
      u0.z = pk2(f1.x, f1.y); u0.w = pk2(f1.z, f1.w);
      u1.x = pk2(f2.x, f2.y); u1.y = pk2(f2.z, f2.w);
      u1.z = pk2(f3.x, f3.y); u1.w = pk2(f3.z, f3.w);
      *(uint4*)&As[srow][kc] = u0;
      *(uint4*)&As[srow][kc + 8] = u1;
    } else {
      const unsigned short* A = (const unsigned short*)Ain + (size_t)(m0 + srow) * 1024 + k0 + kc;
      *(uint4*)&As[srow][kc] = ((const uint4*)A)[0];
      *(uint4*)&As[srow][kc + 8] = ((const uint4*)A)[1];
    }
    {
      const unsigned short* Bp = Bp0 + k0;
      *(uint4*)&Bs[srow][kc] = ((const uint4*)Bp)[0];
      *(uint4*)&Bs[srow][kc + 8] = ((const uint4*)Bp)[1];
    }
    __syncthreads();
    s16x8 af[4], bfr[4];
#pragma unroll
    for (int mt = 0; mt < 4; ++mt) af[mt] = *(const s16x8*)&As[wm + mt * 16 + lr][lg * 8];
#pragma unroll
    for (int nt = 0; nt < 4; ++nt) bfr[nt] = *(const s16x8*)&Bs[wn + nt * 16 + lr][lg * 8];
#pragma unroll
    for (int mt = 0; mt < 4; ++mt)
#pragma unroll
      for (int nt = 0; nt < 4; ++nt)
        acc[mt][nt] = MFMA_BF16(af[mt], bfr[nt], acc[mt][nt]);
    __syncthreads();
  }

  float bcol[4];
#pragma unroll
  for (int nt = 0; nt < 4; ++nt) bcol[nt] = bias[n0 + wn + nt * 16 + lr];

#pragma unroll
  for (int mt = 0; mt < 4; ++mt)
#pragma unroll
    for (int nt = 0; nt < 4; ++nt)
#pragma unroll
      for (int r = 0; r < 4; ++r) {
        float v = acc[mt][nt][r] + bcol[nt];
        int row = m0 + wm + mt * 16 + lg * 4 + r;  // token index (b*2048+s)
        int col = n0 + wn + nt * 16 + lr;          // feature index (h*64+d)
        if constexpr (MODE == 0) {
          int b = row >> 11, s = row & 2047, hh = col >> 6, d = col & 63;
          ((unsigned short*)Cout)[(((size_t)(b * 16 + hh) * 2048 + s) << 6) + d] = f2b(v);
        } else if constexpr (MODE == 1) {
          int b = row >> 11, s = row & 2047, hh = col >> 6, d = col & 63;
          ((unsigned short*)Cout)[(((size_t)(b * 16 + hh) * 64 + d) << 11) + s] = f2b(v);
        } else {
          ((float*)Cout)[(size_t)row * 1024 + col] = v;
        }
      }
}

// ---------------------------------------------------------------------------
// Flash attention, barrier-free. grid = (16 q-tiles, 64 bh), block = 256.
// Each wave owns 32 query rows. Q/K/V fragments read directly from global
// (contiguous 16B per lane in MFMA A/B layout). P round-trips through a
// per-wave LDS region for the C-layout -> A-layout transform.
// ---------------------------------------------------------------------------
__global__ __launch_bounds__(256, 2) void flash_attn(const unsigned short* __restrict__ qh,
                                                     const unsigned short* __restrict__ kh,
                                                     const unsigned short* __restrict__ vt,
                                                     const float* __restrict__ mask,
                                                     unsigned short* __restrict__ ctx) {
  const float c1 = 0.18033688011112042f;    // log2(e)/8  (1/sqrt(64) scale folded into exp2)
  const float c2 = 1.4426950408889634e9f;   // 1e9*log2(e)
  const int bh = blockIdx.y;
  const int b = bh >> 4;
  const int h = bh & 15;
  const int q0 = blockIdx.x << 7;
  const int tid = threadIdx.x;
  const int w = tid >> 6;
  const int lane = tid & 63;
  const int lr = lane & 15;
  const int lg = lane >> 4;

  __shared__ unsigned short Ps[4][32 * 136];  // per-wave P, stride 272 B (16B-aligned)
  unsigned short* myP = Ps[w];

  const unsigned short* qbase = qh + ((size_t)bh * 2048 + q0 + w * 32) * 64;
  const unsigned short* kbase = kh + (size_t)bh * 2048 * 64;
  const unsigned short* vbase = vt + (size_t)bh * 64 * 2048;
  const float* mbase = mask + b * 2048;

  // Q fragments held in registers for the whole kernel
  s16x8 qf[2][2];
#pragma unroll
  for (int mt = 0; mt < 2; ++mt)
#pragma unroll
    for (int kk = 0; kk < 2; ++kk)
      qf[mt][kk] = *(const s16x8*)(qbase + (mt * 16 + lr) * 64 + kk * 32 + lg * 8);

  float m_run[2][4], l_run[2][4];
  f32x4 o_acc[2][4];
#pragma unroll
  for (int mt = 0; mt < 2; ++mt) {
#pragma unroll
    for (int r = 0; r < 4; ++r) {
      m_run[mt][r] = -3.0e38f;
      l_run[mt][r] = 0.0f;
    }
#pragma unroll
    for (int dt = 0; dt < 4; ++dt) {
      f32x4 z = {0.f, 0.f, 0.f, 0.f};
      o_acc[mt][dt] = z;
    }
  }

  for (int t0 = 0; t0 < 2048; t0 += 128) {
    // S = Q K^T  (fp32 accum, MFMA)
    f32x4 sacc[2][8];
#pragma unroll
    for (int mt = 0; mt < 2; ++mt)
#pragma unroll
      for (int nt = 0; nt < 8; ++nt) {
        f32x4 z = {0.f, 0.f, 0.f, 0.f};
        sacc[mt][nt] = z;
      }
#pragma unroll
    for (int nt = 0; nt < 8; ++nt) {
      const unsigned short* kp = kbase + (size_t)(t0 + nt * 16 + lr) * 64 + lg * 8;
      s16x8 kf0 = *(const s16x8*)(kp);
      s16x8 kf1 = *(const s16x8*)(kp + 32);
#pragma unroll
      for (int mt = 0; mt < 2; ++mt) {
        sacc[mt][nt] = MFMA_BF16(qf[mt][0], kf0, sacc[mt][nt]);
        sacc[mt][nt] = MFMA_BF16(qf[mt][1], kf1, sacc[mt][nt]);
      }
    }
    // mask bias per key column (lane holds column lr of each 16-wide tile)
    float mb[8];
#pragma unroll
    for (int nt = 0; nt < 8; ++nt) mb[nt] = mbase[t0 + nt * 16 + lr] * c2;

    // L = dot*log2e/8 - maskbias; row max; online-softmax rescale
#pragma unroll
    for (int mt = 0; mt < 2; ++mt)
#pragma unroll
      for (int r = 0; r < 4; ++r) {
        float mx = -3.0e38f;
#pragma unroll
        for (int nt = 0; nt < 8; ++nt) {
          float L = sacc[mt][nt][r] * c1 - mb[nt];
          sacc[mt][nt][r] = L;
          mx = fmaxf(mx, L);
        }
        mx = fmaxf(mx, __shfl_xor(mx, 1));
        mx = fmaxf(mx, __shfl_xor(mx, 2));
        mx = fmaxf(mx, __shfl_xor(mx, 4));
        mx = fmaxf(mx, __shfl_xor(mx, 8));
        float mn = fmaxf(m_run[mt][r], mx);
        float alpha = fast_exp2(m_run[mt][r] - mn);
        m_run[mt][r] = mn;
        l_run[mt][r] *= alpha;
#pragma unroll
        for (int dt = 0; dt < 4; ++dt) o_acc[mt][dt][r] *= alpha;
      }

    // P = exp2(L - m) -> bf16 -> per-wave LDS (C-layout scatter, b16 writes)
#pragma unroll
    for (int mt = 0; mt < 2; ++mt)
#pragma unroll
      for (int nt = 0; nt < 8; ++nt)
#pragma unroll
        for (int r = 0; r < 4; ++r) {
          float p = fast_exp2(sacc[mt][nt][r] - m_run[mt][r]);
          l_run[mt][r] += p;  // lane-partial row sum; reduced once at the end
          myP[(mt * 16 + lg * 4 + r) * 136 + nt * 16 + lr] = f2b(p);
        }

    // O += P V   (A-frags of P from LDS, B-frags of V^T direct from global)
#pragma unroll
    for (int kt = 0; kt < 4; ++kt) {
      s16x8 pf[2];
#pragma unroll
      for (int mt = 0; mt < 2; ++mt)
        pf[mt] = *(const s16x8*)(myP + (mt * 16 + lr) * 136 + kt * 32 + lg * 8);
#pragma unroll
      for (int dt = 0; dt < 4; ++dt) {
        s16x8 vf = *(const s16x8*)(vbase + (size_t)(dt * 16 + lr) * 2048 + t0 + kt * 32 + lg * 8);
#pragma unroll
        for (int mt = 0; mt < 2; ++mt) o_acc[mt][dt] = MFMA_BF16(pf[mt], vf, o_acc[mt][dt]);
      }
    }
  }

  // final row-sum reduction and normalize; write ctx [B,S,H,D] bf16
  float inv[2][4];
#pragma unroll
  for (int mt = 0; mt < 2; ++mt)
#pragma unroll
    for (int r = 0; r < 4; ++r) {
      float l = l_run[mt][r];
      l += __shfl_xor(l, 1);
      l += __shfl_xor(l, 2);
      l += __shfl_xor(l, 4);
      l += __shfl_xor(l, 8);
      inv[mt][r] = 1.0f / l;
    }
#pragma unroll
  for (int mt = 0; mt < 2; ++mt)
#pragma unroll
    for (int dt = 0; dt < 4; ++dt)
#pragma unroll
      for (int r = 0; r < 4; ++r) {
        int srow = q0 + w * 32 + mt * 16 + lg * 4 + r;
        int d = dt * 16 + lr;
        ctx[((size_t)(b * 2048 + srow) * 16 + h) * 64 + d] = f2b(o_acc[mt][dt][r] * inv[mt][r]);
      }
}

// ---------------------------------------------------------------------------
// Launch pipeline. Workspace layout (72 MB):
//   0: wqt 2MB | 2: wkt | 4: wvt | 6: wot          (bf16 W^T [N,K])
//   8: qh 16MB [B,H,S,D] | 24: kh | 40: vt [B,H,D,S] | 56: ctx 16MB [B,S,H,D]
// ---------------------------------------------------------------------------
extern "C" void kernel_launch(void* const* d_in, const int* in_sizes, int n_in,
                              void* d_out, int out_size, void* d_ws, size_t ws_size,
                              hipStream_t stream) {
  (void)in_sizes; (void)n_in; (void)out_size; (void)ws_size;
  const float* Q = (const float*)d_in[0];
  const float* K = (const float*)d_in[1];
  const float* V = (const float*)d_in[2];
  const float* mask = (const float*)d_in[3];
  const float* Wq = (const float*)d_in[4];
  const float* bq = (const float*)d_in[5];
  const float* Wk = (const float*)d_in[6];
  const float* bk = (const float*)d_in[7];
  const float* Wv = (const float*)d_in[8];
  const float* bv = (const float*)d_in[9];
  const float* Wo = (const float*)d_in[10];
  const float* bo = (const float*)d_in[11];

  char* ws = (char*)d_ws;
  unsigned short* wqt = (unsigned short*)(ws + (size_t)0);
  unsigned short* wkt = (unsigned short*)(ws + ((size_t)2 << 20));
  unsigned short* wvt = (unsigned short*)(ws + ((size_t)4 << 20));
  unsigned short* wot = (unsigned short*)(ws + ((size_t)6 << 20));
  unsigned short* qhb = (unsigned short*)(ws + ((size_t)8 << 20));
  unsigned short* khb = (unsigned short*)(ws + ((size_t)24 << 20));
  unsigned short* vtb = (unsigned short*)(ws + ((size_t)40 << 20));
  unsigned short* ctx = (unsigned short*)(ws + ((size_t)56 << 20));

  wtrans<<<dim3(32, 32, 4), dim3(32, 8), 0, stream>>>(Wq, Wk, Wv, Wo, wqt, wkt, wvt, wot);

  dim3 gg(8, 64), bb(256);
  gemm_bt<0><<<gg, bb, 0, stream>>>(Q, wqt, bq, qhb);
  gemm_bt<0><<<gg, bb, 0, stream>>>(K, wkt, bk, khb);
  gemm_bt<1><<<gg, bb, 0, stream>>>(V, wvt, bv, vtb);

  flash_attn<<<dim3(16, 64), 256, 0, stream>>>(qhb, khb, vtb, mask, ctx);

  gemm_bt<2><<<gg, bb, 0, stream>>>(ctx, wot, bo, d_out);
}